// Round 4
// baseline (299.324 us; speedup 1.0000x reference)
//
#include <hip/hip_runtime.h>
#include <cstdint>
#include <cstddef>

// Problem: B=8, C=64, H=W=32 -> N=8192 nodes, K=9 neighbors, OUT=64.
// Batches: b = [1024b,1024(b+1)) for b<=6, batch 7 = [7168,8190], batch 8 = {8191}.
// Node g <-> (b = g>>10, hw = g&1023); features x[b][c][hw] (node 8191 -> b=7).
//
// R10: gap-dominated regime confirmed (R6..R9 fill-normalized totals identical;
//  ~6us per graph node x 8 nodes/iter). 2 kernels -> 1 via SOFTWARE grid
//  barrier (R8's cooperative launch no-ops under graph capture):
//   - 352 phase-A blocks (288 triangular dist tiles + 64 W tiles) each set a
//     per-block flag = MAGIC (release, agent scope) after syncthreads (vmcnt
//     drain) + threadfence (L2 writeback).
//   - Per-iteration workspace POISON resets flags (poison is a repeated-byte
//     pattern; MAGIC is not) -> no init race across graph replays.
//   - All 512 blocks' wave 0 poll the 352 flags with agent-scope acquire
//     loads (no RMW hot lines) + s_sleep backoff. Readers' L2 is cold on
//     D/yl/yr lines -> post-barrier loads fetch fenced data. grid 512 ==
//     co-residency capacity at launch_bounds(256,2) -> no deadlock.
//  Phase A/B logic is R9's proven code verbatim.

#define BARRIER_MAGIC 0x1F2E3D4Cu

__global__ __launch_bounds__(256, 2) void k_fused(const float* __restrict__ x,
                                                  const float* __restrict__ Wl,
                                                  const float* __restrict__ Wr,
                                                  const float* __restrict__ bl,
                                                  float* __restrict__ yl,
                                                  float* __restrict__ yr,
                                                  float* __restrict__ D,
                                                  unsigned* __restrict__ flags,
                                                  float* __restrict__ out) {
  __shared__ float4 SH[2112];          // As4[1056] | Bs4[1056]; reused as [64][132] f32 transpose buf
  float4* As4 = SH;
  float4* Bs4 = SH + 1056;
  __shared__ float sqA[128];
  __shared__ float sqB[128];
  int bi = (int)blockIdx.x;
  int t = threadIdx.x;
  int tx = t & 15, ty = t >> 4;        // 16x16 thread grid

  // ------------------------------- Phase A --------------------------------
  if (bi < 352) {
    bool is_w = (bi >= 288);
    int i0, j0 = 0, sb = 0, ti = 0, tj = 0;
    if (is_w) {
      i0 = (bi - 288) << 7;            // i-tile 0..63
    } else {
      int b = bi / 36;                 // batch
      int rem = bi - b * 36;           // triangular: row ti has 8-ti entries
      while (rem >= 8 - ti) { rem -= (8 - ti); ++ti; }
      tj = ti + rem;
      sb = b << 10;
      i0 = sb + (ti << 7);
      j0 = sb + (tj << 7);
    }
    const float* xA = x + (((size_t)(i0 >> 10)) << 16) + (i0 & 1023);
    const float* xB = is_w ? xA : x + (((size_t)(j0 >> 10)) << 16) + (j0 & 1023);

    float acc[8][8];
#pragma unroll
    for (int r = 0; r < 8; ++r)
#pragma unroll
      for (int c = 0; c < 8; ++c) acc[r][c] = 0.f;

#pragma unroll 1
    for (int pass = 0; pass < 2; ++pass) {
      if (pass) __syncthreads();       // prev-pass LDS reads done before restage
      int c0 = pass << 5;
      // stage A: u = t+256i; c = u>>5 (coalesced 128B rows), m4 = u&31
#pragma unroll
      for (int i = 0; i < 4; ++i) {
        int u = t + (i << 8);
        int c = u >> 5, m4 = u & 31;
        As4[c * 33 + m4] = *(const float4*)&xA[((size_t)(c0 + c) << 10) + (m4 << 2)];
      }
      if (!is_w) {
#pragma unroll
        for (int i = 0; i < 4; ++i) {
          int u = t + (i << 8);
          int c = u >> 5, m4 = u & 31;
          Bs4[c * 33 + m4] = *(const float4*)&xB[((size_t)(c0 + c) << 10) + (m4 << 2)];
        }
      } else {
        // stage Wcat[j][c0+c]: j<64 -> Wl row j, else Wr row j-64
#pragma unroll
        for (int i = 0; i < 16; ++i) {
          int u = t + (i << 8);
          int j = u >> 5, c = u & 31;
          const float* Wsrc = (j < 64) ? Wl : Wr;
          int jr = j & 63;
          ((float*)&Bs4[c * 33 + (j >> 2)])[j & 3] = Wsrc[(jr << 6) + c0 + c];
        }
      }
      __syncthreads();
      // sq partial (dist blocks only): ascending-c fmaf chain == dot chain ->
      // d(i,i) cancels exactly (and mirror tiles are bitwise-equal).
      if (!is_w) {
        int m = t & 127;
        const float* base = (t < 128) ? (const float*)As4 : (const float*)Bs4;
        float p = 0.f;
#pragma unroll
        for (int c = 0; c < 32; ++c) {
          float v = base[(c * 33 + (m >> 2)) * 4 + (m & 3)];
          p = fmaf(v, v, p);
        }
        float* dst = (t < 128) ? sqA : sqB;
        if (pass == 0) dst[m] = p; else dst[m] += p;
      }
      // GEMM: per k, 4 ds_read_b128 frags + 64 FMA
#pragma unroll 4
      for (int k = 0; k < 32; ++k) {
        float4 a0 = As4[k * 33 + ty];
        float4 a1 = As4[k * 33 + 16 + ty];
        float4 b0 = Bs4[k * 33 + tx];
        float4 b1 = Bs4[k * 33 + 16 + tx];
        float av[8] = {a0.x, a0.y, a0.z, a0.w, a1.x, a1.y, a1.z, a1.w};
        float bv[8] = {b0.x, b0.y, b0.z, b0.w, b1.x, b1.y, b1.z, b1.w};
#pragma unroll
        for (int r = 0; r < 8; ++r)
#pragma unroll
          for (int c = 0; c < 8; ++c)
            acc[r][c] = fmaf(av[r], bv[c], acc[r][c]);
      }
    }
    __syncthreads();                   // GEMM LDS reads + sq writes complete

    int rloc[8];
#pragma unroll
    for (int r = 0; r < 4; ++r) { rloc[r] = (ty << 2) + r; rloc[4 + r] = 64 + (ty << 2) + r; }

    if (is_w) {
      // acc[r][0..3] = y_l[n][4tx..], acc[r][4..7] = y_r[n][4tx..]
      float4 blv = *(const float4*)&bl[tx << 2];
#pragma unroll
      for (int r = 0; r < 8; ++r) {
        int n = i0 + rloc[r];
        float4 o0, o1;
        o0.x = acc[r][0]; o0.y = acc[r][1]; o0.z = acc[r][2]; o0.w = acc[r][3];
        o1.x = acc[r][4] + blv.x; o1.y = acc[r][5] + blv.y;
        o1.z = acc[r][6] + blv.z; o1.w = acc[r][7] + blv.w;
        *(float4*)&yl[((size_t)n << 6) + (tx << 2)] = o0;
        *(float4*)&yr[((size_t)n << 6) + (tx << 2)] = o1;
      }
    } else {
      int cloc[8];
#pragma unroll
      for (int c = 0; c < 4; ++c) { cloc[c] = (tx << 2) + c; cloc[4 + c] = 64 + (tx << 2) + c; }
      float sqi[8], sqj[8];
#pragma unroll
      for (int r = 0; r < 8; ++r) sqi[r] = sqA[rloc[r]];
#pragma unroll
      for (int c = 0; c < 8; ++c) sqj[c] = sqB[cloc[c]];
      // fold final distance into acc
#pragma unroll
      for (int r = 0; r < 8; ++r)
#pragma unroll
        for (int c = 0; c < 8; ++c)
          acc[r][c] = sqi[r] + sqj[c] - 2.f * acc[r][c];
      // own tile: rows i0+rloc, cols (j0-sb)+cloc
#pragma unroll
      for (int r = 0; r < 8; ++r) {
        size_t rb = ((size_t)(i0 + rloc[r]) << 10) + (j0 - sb);
        float4 o0, o1;
        o0.x = acc[r][0]; o0.y = acc[r][1]; o0.z = acc[r][2]; o0.w = acc[r][3];
        o1.x = acc[r][4]; o1.y = acc[r][5]; o1.z = acc[r][6]; o1.w = acc[r][7];
        *(float4*)&D[rb + (tx << 2)] = o0;
        *(float4*)&D[rb + 64 + (tx << 2)] = o1;
      }
      if (ti != tj) {
        // mirror tile via LDS restage: half h = cols 64h..64h+63 of own tile =
        // rows j0+64h..+63 of mirror. tb is [64][132] f32.
        float* tb = (float*)SH;
#pragma unroll 1
        for (int h = 0; h < 2; ++h) {
          __syncthreads();             // prior LDS consumers done
#pragma unroll
          for (int r = 0; r < 8; ++r)
#pragma unroll
            for (int c = 0; c < 4; ++c)
              tb[((tx << 2) + c) * 132 + rloc[r]] = acc[r][(h << 2) + c];
          __syncthreads();
#pragma unroll
          for (int it = 0; it < 8; ++it) {
            int lin = t + (it << 8);
            int j2 = lin >> 5, u = lin & 31;
            float4 v = *(const float4*)&tb[j2 * 132 + (u << 2)];
            *(float4*)&D[((size_t)(j0 + (h << 6) + j2) << 10) + (i0 - sb) + (u << 2)] = v;
          }
        }
      }
    }
    // arrive: all threads' stores issued + at L2 (syncthreads drains vmcnt),
    // then one release-store of this block's flag.
    __syncthreads();
    if (t == 0) {
      __threadfence();                 // L2 writeback to device coherence point
      __hip_atomic_store(&flags[bi << 4], BARRIER_MAGIC, __ATOMIC_RELEASE,
                         __HIP_MEMORY_SCOPE_AGENT);
    }
  }

  // ------------------------- software grid barrier ------------------------
  if (t < 64) {
    bool done = false;
    while (!done) {
      bool ok = true;
#pragma unroll
      for (int q = 0; q < 6; ++q) {
        int idx = t + (q << 6);        // lane covers flags idx, idx+64, ...
        unsigned v = (idx < 352)
            ? __hip_atomic_load(&flags[idx << 4], __ATOMIC_ACQUIRE,
                                __HIP_MEMORY_SCOPE_AGENT)
            : BARRIER_MAGIC;
        ok &= (v == BARRIER_MAGIC);
      }
      done = __all(ok);
      if (!done) __builtin_amdgcn_s_sleep(8);
    }
    __threadfence();                   // acquire side: no stale cache lines
  }
  __syncthreads();

  // ------------------------------- Phase B --------------------------------
  // 512 blocks x 16 rows; wave w owns rows bi*16 + 4w .. +3 (serial).
  int lane = t & 63;
  int w = t >> 6;
  int n0 = (bi << 4) + (w << 2);
#pragma unroll 1
  for (int rr = 0; rr < 4; ++rr) {
    int n = n0 + rr;
    float rv = yr[((size_t)n << 6) + lane];   // bias already folded
    float accv;
    if (n == 8191) {                          // singleton batch: self only
      accv = yl[((size_t)n << 6) + lane];
    } else {
      int s = (n >= 7168) ? 7168 : (n & ~1023);
      bool mlast = (n >= 7168);               // batch-7 rows exclude node 8191
      const float* drow = D + ((size_t)n << 10);
      unsigned long long cand[16];
#pragma unroll
      for (int q = 0; q < 4; ++q) {
        float4 v = *(const float4*)&drow[(q << 8) + (lane << 2)];
        float vv[4] = {v.x, v.y, v.z, v.w};
#pragma unroll
        for (int e = 0; e < 4; ++e) {
          unsigned u = __float_as_uint(vv[e]);
          u = (u & 0x80000000u) ? ~u : (u | 0x80000000u);
          unsigned jj = (unsigned)((q << 8) + (lane << 2) + e);
          cand[(q << 2) + e] = ((unsigned long long)u << 32) | jj;
        }
      }
      if (mlast && lane == 63) cand[15] = ~0ull;   // jj=1023 -> q=3,lane=63,e=3
      // per-lane top-2 cache
      unsigned long long m1 = cand[0], m2 = cand[1];
      if (m2 < m1) { unsigned long long tt = m1; m1 = m2; m2 = tt; }
#pragma unroll
      for (int q = 2; q < 16; ++q) {
        unsigned long long c = cand[q];
        unsigned long long lo = (c < m1) ? c : m1;
        unsigned long long hi = (c < m1) ? m1 : c;
        m2 = (hi < m2) ? hi : m2;
        m1 = lo;
      }
      unsigned long long lm = m1;
      unsigned rmask = 0;
      bool stale = false;
      unsigned j9[9];
#pragma unroll
      for (int kk = 0; kk < 9; ++kk) {
        unsigned long long g = lm;
#pragma unroll
        for (int off = 32; off; off >>= 1) {
          unsigned ghi = __shfl_xor((unsigned)(g >> 32), off, 64);
          unsigned glo = __shfl_xor((unsigned)g, off, 64);
          unsigned long long o = ((unsigned long long)ghi << 32) | glo;
          g = (o < g) ? o : g;
        }
        j9[kk] = (unsigned)s + ((unsigned)g & 1023u);
        if (lm == g) {                // exactly one winner lane (unique keys)
          unsigned slot = (((unsigned)g >> 6) & 12u) | ((unsigned)g & 3u);
          rmask |= 1u << slot;
          if (!stale) { lm = m2; stale = true; }
          else {                      // rare: rescan excluding removed slots
            unsigned long long best = ~0ull;
#pragma unroll
            for (int q = 0; q < 16; ++q) {
              bool alive = ((rmask >> q) & 1u) == 0u;
              unsigned long long c = cand[q];
              best = (alive && c < best) ? c : best;
            }
            lm = best;
          }
        }
      }
      // 9 independent gathers (uniform rows -> coalesced 256B), tree sum
      float g0 = yl[((size_t)j9[0] << 6) + lane];
      float g1 = yl[((size_t)j9[1] << 6) + lane];
      float g2 = yl[((size_t)j9[2] << 6) + lane];
      float g3 = yl[((size_t)j9[3] << 6) + lane];
      float g4 = yl[((size_t)j9[4] << 6) + lane];
      float g5 = yl[((size_t)j9[5] << 6) + lane];
      float g6 = yl[((size_t)j9[6] << 6) + lane];
      float g7 = yl[((size_t)j9[7] << 6) + lane];
      float g8 = yl[((size_t)j9[8] << 6) + lane];
      accv = (((g0 + g1) + (g2 + g3)) + ((g4 + g5) + (g6 + g7)) + g8) * (1.f / 9.f);
    }
    out[((size_t)n << 6) + lane] = accv + rv;
  }
}

// ---------------------------------------------------------------------------
extern "C" void kernel_launch(void* const* d_in, const int* in_sizes, int n_in,
                              void* d_out, int out_size, void* d_ws, size_t ws_size,
                              hipStream_t stream) {
  const float* x  = (const float*)d_in[0];   // (8,64,32,32)
  const float* Wl = (const float*)d_in[1];   // (64,64)
  const float* bl = (const float*)d_in[2];   // (64,)
  const float* Wr = (const float*)d_in[3];   // (64,64)
  float* out = (float*)d_out;                // (8192,64)

  char* ws = (char*)d_ws;
  float* yl = (float*)(ws);                  //  2 MB: xf @ Wl^T
  float* yr = (float*)(ws + 2097152);        //  2 MB: xf @ Wr^T + bl
  float* D  = (float*)(ws + 4194304);        // 32 MB: distances
  unsigned* flags = (unsigned*)(ws + 37748736); // 352 flags, 64B stride (22.5KB)

  k_fused<<<dim3(512), 256, 0, stream>>>(x, Wl, Wr, bl, yl, yr, D, flags, out);
}

// Round 6
// 108.575 us; speedup vs baseline: 2.7568x; 2.7568x over previous
//
#include <hip/hip_runtime.h>
#include <cstdint>
#include <cstddef>

// Problem: B=8, C=64, H=W=32 -> N=8192 nodes, K=9 neighbors, OUT=64.
// Batches: b = [1024b,1024(b+1)) for b<=6, batch 7 = [7168,8190], batch 8 = {8191}.
// Node g <-> (b = g>>10, hw = g&1023); features x[b][c][hw] (node 8191 -> b=7).
//
// R12: R11 retry — __builtin_nontemporal_* requires native vector types, not
//  HIP_vector_type<float,4>; route through ext_vector_type(4) float (same
//  layout). Theory unchanged: D is 32MB stream-once (write in k_dist, read in
//  k_selout) -> nontemporal keeps L2 for reused data (x, W, yl/yr).
//  k_dist grid = 352: 288 triangular dist tiles (D bitwise-symmetric: identical
//  fmaf chains both orientations; off-diag tiles write the mirror via
//  LDS-restaged transpose) + 64 W tiles (y_l = xf@Wl^T, y_r' = xf@Wr^T + b;
//  mean/linear commute). k_selout: top-9 tournament + y-gathers, 2048 blocks.

typedef float nf4 __attribute__((ext_vector_type(4)));   // nt-builtin-legal f32x4

// ---------------------------------------------------------------------------
__global__ __launch_bounds__(256, 2) void k_dist(const float* __restrict__ x,
                                                 const float* __restrict__ Wl,
                                                 const float* __restrict__ Wr,
                                                 const float* __restrict__ bl,
                                                 float* __restrict__ yl,
                                                 float* __restrict__ yr,
                                                 float* __restrict__ D) {
  __shared__ float4 SH[2112];          // As4[1056] | Bs4[1056]; reused as [64][132] f32 transpose buf
  float4* As4 = SH;
  float4* Bs4 = SH + 1056;
  __shared__ float sqA[128];
  __shared__ float sqB[128];
  int bi = (int)blockIdx.x;
  int t = threadIdx.x;
  int tx = t & 15, ty = t >> 4;        // 16x16 thread grid

  bool is_w = (bi >= 288);
  int i0, j0 = 0, sb = 0, ti = 0, tj = 0;
  if (is_w) {
    i0 = (bi - 288) << 7;              // i-tile 0..63
  } else {
    int b = bi / 36;                   // batch
    int rem = bi - b * 36;             // triangular: row ti has 8-ti entries
    while (rem >= 8 - ti) { rem -= (8 - ti); ++ti; }
    tj = ti + rem;
    sb = b << 10;
    i0 = sb + (ti << 7);
    j0 = sb + (tj << 7);
  }
  const float* xA = x + (((size_t)(i0 >> 10)) << 16) + (i0 & 1023);
  const float* xB = is_w ? xA : x + (((size_t)(j0 >> 10)) << 16) + (j0 & 1023);

  float acc[8][8];
#pragma unroll
  for (int r = 0; r < 8; ++r)
#pragma unroll
    for (int c = 0; c < 8; ++c) acc[r][c] = 0.f;

#pragma unroll 1
  for (int pass = 0; pass < 2; ++pass) {
    if (pass) __syncthreads();         // prev-pass LDS reads done before restage
    int c0 = pass << 5;
    // stage A: u = t+256i; c = u>>5 (coalesced 128B rows), m4 = u&31
#pragma unroll
    for (int i = 0; i < 4; ++i) {
      int u = t + (i << 8);
      int c = u >> 5, m4 = u & 31;
      As4[c * 33 + m4] = *(const float4*)&xA[((size_t)(c0 + c) << 10) + (m4 << 2)];
    }
    if (!is_w) {
#pragma unroll
      for (int i = 0; i < 4; ++i) {
        int u = t + (i << 8);
        int c = u >> 5, m4 = u & 31;
        Bs4[c * 33 + m4] = *(const float4*)&xB[((size_t)(c0 + c) << 10) + (m4 << 2)];
      }
    } else {
      // stage Wcat[j][c0+c]: j<64 -> Wl row j, else Wr row j-64
#pragma unroll
      for (int i = 0; i < 16; ++i) {
        int u = t + (i << 8);
        int j = u >> 5, c = u & 31;
        const float* Wsrc = (j < 64) ? Wl : Wr;
        int jr = j & 63;
        ((float*)&Bs4[c * 33 + (j >> 2)])[j & 3] = Wsrc[(jr << 6) + c0 + c];
      }
    }
    __syncthreads();
    // sq partial (dist blocks only): ascending-c fmaf chain == dot chain ->
    // d(i,i) cancels exactly (and mirror tiles are bitwise-equal).
    if (!is_w) {
      int m = t & 127;
      const float* base = (t < 128) ? (const float*)As4 : (const float*)Bs4;
      float p = 0.f;
#pragma unroll
      for (int c = 0; c < 32; ++c) {
        float v = base[(c * 33 + (m >> 2)) * 4 + (m & 3)];
        p = fmaf(v, v, p);
      }
      float* dst = (t < 128) ? sqA : sqB;
      if (pass == 0) dst[m] = p; else dst[m] += p;
    }
    // GEMM: per k, 4 ds_read_b128 frags + 64 FMA
#pragma unroll 4
    for (int k = 0; k < 32; ++k) {
      float4 a0 = As4[k * 33 + ty];
      float4 a1 = As4[k * 33 + 16 + ty];
      float4 b0 = Bs4[k * 33 + tx];
      float4 b1 = Bs4[k * 33 + 16 + tx];
      float av[8] = {a0.x, a0.y, a0.z, a0.w, a1.x, a1.y, a1.z, a1.w};
      float bv[8] = {b0.x, b0.y, b0.z, b0.w, b1.x, b1.y, b1.z, b1.w};
#pragma unroll
      for (int r = 0; r < 8; ++r)
#pragma unroll
        for (int c = 0; c < 8; ++c)
          acc[r][c] = fmaf(av[r], bv[c], acc[r][c]);
    }
  }
  __syncthreads();                     // GEMM LDS reads + sq writes complete

  int rloc[8];
#pragma unroll
  for (int r = 0; r < 4; ++r) { rloc[r] = (ty << 2) + r; rloc[4 + r] = 64 + (ty << 2) + r; }

  if (is_w) {
    // acc[r][0..3] = y_l[n][4tx..], acc[r][4..7] = y_r[n][4tx..]
    float4 blv = *(const float4*)&bl[tx << 2];
#pragma unroll
    for (int r = 0; r < 8; ++r) {
      int n = i0 + rloc[r];
      float4 o0, o1;
      o0.x = acc[r][0]; o0.y = acc[r][1]; o0.z = acc[r][2]; o0.w = acc[r][3];
      o1.x = acc[r][4] + blv.x; o1.y = acc[r][5] + blv.y;
      o1.z = acc[r][6] + blv.z; o1.w = acc[r][7] + blv.w;
      *(float4*)&yl[((size_t)n << 6) + (tx << 2)] = o0;
      *(float4*)&yr[((size_t)n << 6) + (tx << 2)] = o1;
    }
    return;
  }

  int cloc[8];
#pragma unroll
  for (int c = 0; c < 4; ++c) { cloc[c] = (tx << 2) + c; cloc[4 + c] = 64 + (tx << 2) + c; }
  float sqi[8], sqj[8];
#pragma unroll
  for (int r = 0; r < 8; ++r) sqi[r] = sqA[rloc[r]];
#pragma unroll
  for (int c = 0; c < 8; ++c) sqj[c] = sqB[cloc[c]];
  // fold final distance into acc
#pragma unroll
  for (int r = 0; r < 8; ++r)
#pragma unroll
    for (int c = 0; c < 8; ++c)
      acc[r][c] = sqi[r] + sqj[c] - 2.f * acc[r][c];
  // own tile: rows i0+rloc, cols (j0-sb)+cloc. D is stream-once -> nt stores.
#pragma unroll
  for (int r = 0; r < 8; ++r) {
    size_t rb = ((size_t)(i0 + rloc[r]) << 10) + (j0 - sb);
    nf4 o0 = {acc[r][0], acc[r][1], acc[r][2], acc[r][3]};
    nf4 o1 = {acc[r][4], acc[r][5], acc[r][6], acc[r][7]};
    __builtin_nontemporal_store(o0, (nf4*)&D[rb + (tx << 2)]);
    __builtin_nontemporal_store(o1, (nf4*)&D[rb + 64 + (tx << 2)]);
  }
  if (ti != tj) {
    // mirror tile via LDS restage: half h = cols 64h..64h+63 of own tile =
    // rows j0+64h..+63 of mirror. tb is [64][132] f32.
    float* tb = (float*)SH;
#pragma unroll 1
    for (int h = 0; h < 2; ++h) {
      __syncthreads();                 // prior LDS consumers done
#pragma unroll
      for (int r = 0; r < 8; ++r)
#pragma unroll
        for (int c = 0; c < 4; ++c)
          tb[((tx << 2) + c) * 132 + rloc[r]] = acc[r][(h << 2) + c];
      __syncthreads();
#pragma unroll
      for (int it = 0; it < 8; ++it) {
        int lin = t + (it << 8);
        int j2 = lin >> 5, u = lin & 31;
        nf4 v = *(const nf4*)&tb[j2 * 132 + (u << 2)];
        __builtin_nontemporal_store(
            v, (nf4*)&D[((size_t)(j0 + (h << 6) + j2) << 10) + (i0 - sb) + (u << 2)]);
      }
    }
  }
}

// ---------------------------------------------------------------------------
// k_selout: top-9 select + gather of precomputed y rows. 2048 blocks x 4
// waves, 1 row per wave. Key = (orderable-dist << 32) | jj, jj = 256q+4*lane+e
// (per-instruction contiguous 1KB float4 reads) -> unique keys, smaller-index
// tie-break (matches lax.top_k). D row loads are read-once -> nt loads.
// ---------------------------------------------------------------------------
__global__ __launch_bounds__(256, 4) void k_selout(const float* __restrict__ D,
                                                   const float* __restrict__ yl,
                                                   const float* __restrict__ yr,
                                                   float* __restrict__ out) {
  int t = threadIdx.x;
  int lane = t & 63;
  int w = t >> 6;
  int n = ((int)blockIdx.x << 2) + w;

  float rv = yr[((size_t)n << 6) + lane];   // issue early (bias already folded)
  float acc;
  if (n == 8191) {                          // singleton batch: self only
    acc = yl[((size_t)n << 6) + lane];
  } else {
    int s = (n >= 7168) ? 7168 : (n & ~1023);
    bool mlast = (n >= 7168);               // batch-7 rows exclude node 8191
    const float* drow = D + ((size_t)n << 10);
    unsigned long long cand[16];
#pragma unroll
    for (int q = 0; q < 4; ++q) {
      nf4 v = __builtin_nontemporal_load(
          (const nf4*)&drow[(q << 8) + (lane << 2)]);
      float vv[4] = {v.x, v.y, v.z, v.w};
#pragma unroll
      for (int e = 0; e < 4; ++e) {
        unsigned u = __float_as_uint(vv[e]);
        u = (u & 0x80000000u) ? ~u : (u | 0x80000000u);
        unsigned jj = (unsigned)((q << 8) + (lane << 2) + e);
        cand[(q << 2) + e] = ((unsigned long long)u << 32) | jj;
      }
    }
    if (mlast && lane == 63) cand[15] = ~0ull;   // jj=1023 -> q=3,lane=63,e=3
    // per-lane top-2 cache
    unsigned long long m1 = cand[0], m2 = cand[1];
    if (m2 < m1) { unsigned long long tt = m1; m1 = m2; m2 = tt; }
#pragma unroll
    for (int q = 2; q < 16; ++q) {
      unsigned long long c = cand[q];
      unsigned long long lo = (c < m1) ? c : m1;
      unsigned long long hi = (c < m1) ? m1 : c;
      m2 = (hi < m2) ? hi : m2;
      m1 = lo;
    }
    unsigned long long lm = m1;
    unsigned rmask = 0;
    bool stale = false;
    unsigned j9[9];
#pragma unroll
    for (int kk = 0; kk < 9; ++kk) {
      unsigned long long g = lm;
#pragma unroll
      for (int off = 32; off; off >>= 1) {
        unsigned ghi = __shfl_xor((unsigned)(g >> 32), off, 64);
        unsigned glo = __shfl_xor((unsigned)g, off, 64);
        unsigned long long o = ((unsigned long long)ghi << 32) | glo;
        g = (o < g) ? o : g;
      }
      j9[kk] = (unsigned)s + ((unsigned)g & 1023u);
      if (lm == g) {                // exactly one winner lane (unique keys)
        unsigned slot = (((unsigned)g >> 6) & 12u) | ((unsigned)g & 3u);
        rmask |= 1u << slot;
        if (!stale) { lm = m2; stale = true; }
        else {                      // rare: rescan excluding removed slots
          unsigned long long best = ~0ull;
#pragma unroll
          for (int q = 0; q < 16; ++q) {
            bool alive = ((rmask >> q) & 1u) == 0u;
            unsigned long long c = cand[q];
            best = (alive && c < best) ? c : best;
          }
          lm = best;
        }
      }
    }
    // 9 independent gathers (uniform rows -> coalesced 256B), tree sum
    float g0 = yl[((size_t)j9[0] << 6) + lane];
    float g1 = yl[((size_t)j9[1] << 6) + lane];
    float g2 = yl[((size_t)j9[2] << 6) + lane];
    float g3 = yl[((size_t)j9[3] << 6) + lane];
    float g4 = yl[((size_t)j9[4] << 6) + lane];
    float g5 = yl[((size_t)j9[5] << 6) + lane];
    float g6 = yl[((size_t)j9[6] << 6) + lane];
    float g7 = yl[((size_t)j9[7] << 6) + lane];
    float g8 = yl[((size_t)j9[8] << 6) + lane];
    acc = (((g0 + g1) + (g2 + g3)) + ((g4 + g5) + (g6 + g7)) + g8) * (1.f / 9.f);
  }
  __builtin_nontemporal_store(acc + rv, &out[((size_t)n << 6) + lane]);
}

// ---------------------------------------------------------------------------
extern "C" void kernel_launch(void* const* d_in, const int* in_sizes, int n_in,
                              void* d_out, int out_size, void* d_ws, size_t ws_size,
                              hipStream_t stream) {
  const float* x  = (const float*)d_in[0];   // (8,64,32,32)
  const float* Wl = (const float*)d_in[1];   // (64,64)
  const float* bl = (const float*)d_in[2];   // (64,)
  const float* Wr = (const float*)d_in[3];   // (64,64)
  float* out = (float*)d_out;                // (8192,64)

  char* ws = (char*)d_ws;
  float* yl = (float*)(ws);                  //  2 MB: xf @ Wl^T
  float* yr = (float*)(ws + 2097152);        //  2 MB: xf @ Wr^T + bl
  float* D  = (float*)(ws + 4194304);        // 32 MB: distances

  k_dist<<<dim3(352), 256, 0, stream>>>(x, Wl, Wr, bl, yl, yr, D);
  k_selout<<<2048, 256, 0, stream>>>(D, yl, yr, out);
}

// Round 7
// 104.571 us; speedup vs baseline: 2.8624x; 1.0383x over previous
//
#include <hip/hip_runtime.h>
#include <cstdint>
#include <cstddef>

// Problem: B=8, C=64, H=W=32 -> N=8192 nodes, K=9 neighbors, OUT=64.
// Batches: b = [1024b,1024(b+1)) for b<=6, batch 7 = [7168,8190], batch 8 = {8191}.
// Node g <-> (b = g>>10, hw = g&1023); features x[b][c][hw] (node 8191 -> b=7).
//
// R13: single self-sufficient kernel, no D buffer, no workspace, no 2nd launch.
//  512 blocks x 16 rows. Per block: stage own-batch X in 4 K-slices (LDS
//  region0, [ch][col4] f4 planes; NCHW is K-major -> no transpose), 8x8/thread
//  register GEMM (A-reads wave-broadcast) -> full 16x1024 dist tile -> write
//  into region0 (X dead) -> R12 tournament per wave-row from LDS -> overlay
//  Ws into region0 -> readlane transform out = mean(x_nbr)@Wl^T + x_n@Wr^T + b
//  (mean-then-linear = exactly the reference order).
//  Exact self-cancel: sq and dot are identical ascending-channel fmaf chains
//  on bitwise-identical staged values -> d(n,n) == 0. Keys (dist|jj) unique ->
//  lax.top_k tie-break preserved. LDS 72KB -> 2 blocks/CU; grid 512 = one
//  occupancy round. All LDS patterns stride-1 or broadcast -> ~0 conflicts.

typedef float nf4 __attribute__((ext_vector_type(4)));   // nt-builtin-legal f32x4

__global__ __launch_bounds__(256, 2) void k_all(const float* __restrict__ x,
                                                const float* __restrict__ Wl,
                                                const float* __restrict__ bl,
                                                const float* __restrict__ Wr,
                                                float* __restrict__ out) {
  __shared__ float R0[16384];        // 64KB: Xs (f4[16][256]) -> dist f32[16][1024] -> Ws
  __shared__ float Asf[1024];        // 4KB: As4[c][r4] (16 rows x 64 ch)
  __shared__ float sqX[1024];        // 4KB: per-col |x|^2 (ascending-c chain)
  float4* Xs4 = (float4*)R0;
  float4* As4 = (float4*)Asf;
  float4* sqX4 = (float4*)sqX;

  int bi = (int)blockIdx.x, t = threadIdx.x;
  int n0 = bi << 4;                  // 16-aligned; all batch bounds 16-aligned
  int s = (n0 >= 7168) ? 7168 : (n0 & ~1023);
  const float* xb = x + (((size_t)(s >> 10)) << 16);     // batch base (cols)
  const float* xrow = x + (((size_t)(n0 >> 10)) << 16) + (n0 & 1023);

  // stage A: 16 rows x 64 ch, one f4 (4 consecutive rows) per thread
  {
    int c = t >> 2, r4 = t & 3;
    As4[(c << 2) + r4] = *(const float4*)&xrow[((size_t)c << 10) + (r4 << 2)];
  }

  float acc[8][8];
#pragma unroll
  for (int r = 0; r < 8; ++r)
#pragma unroll
    for (int c = 0; c < 8; ++c) acc[r][c] = 0.f;
  float4 p4 = {0.f, 0.f, 0.f, 0.f};  // sq partials for cols 4t..4t+3
  int h = t >> 7, cg = t & 127;      // thread tile: rows 8h..8h+7, cols {4cg..,512+4cg..}

#pragma unroll 1
  for (int ks = 0; ks < 4; ++ks) {
    if (ks) __syncthreads();         // prev-slice LDS reads done before restage
    int k0 = ks << 4;
    // stage Xs slice: 16 ch x 1024 cols, f4 direct copy (coalesced 1KB/instr)
#pragma unroll 4
    for (int i = 0; i < 16; ++i) {
      int lin = t + (i << 8);
      int kc = lin >> 8, j4 = lin & 255;
      Xs4[(kc << 8) + j4] =
          *(const float4*)&xb[((size_t)(k0 + kc) << 10) + (j4 << 2)];
    }
    __syncthreads();
    // sq partial: ascending-channel fmaf chain == dot chain -> exact cancel
#pragma unroll
    for (int kc = 0; kc < 16; ++kc) {
      float4 v = Xs4[(kc << 8) + t];
      p4.x = fmaf(v.x, v.x, p4.x);
      p4.y = fmaf(v.y, v.y, p4.y);
      p4.z = fmaf(v.z, v.z, p4.z);
      p4.w = fmaf(v.w, v.w, p4.w);
    }
    // GEMM: per channel, 2 broadcast A-reads + 2 stride-1 B-reads + 64 FMA
#pragma unroll
    for (int kc = 0; kc < 16; ++kc) {
      float4 a0 = As4[((k0 + kc) << 2) + (h << 1)];      // rows 8h..8h+3
      float4 a1 = As4[((k0 + kc) << 2) + (h << 1) + 1];  // rows 8h+4..8h+7
      float4 b0 = Xs4[(kc << 8) + cg];                   // cols 4cg..4cg+3
      float4 b1 = Xs4[(kc << 8) + 128 + cg];             // cols 512+4cg..
      float av[8] = {a0.x, a0.y, a0.z, a0.w, a1.x, a1.y, a1.z, a1.w};
      float bv[8] = {b0.x, b0.y, b0.z, b0.w, b1.x, b1.y, b1.z, b1.w};
#pragma unroll
      for (int r = 0; r < 8; ++r)
#pragma unroll
        for (int c = 0; c < 8; ++c)
          acc[r][c] = fmaf(av[r], bv[c], acc[r][c]);
    }
  }
  sqX4[t] = p4;
  __syncthreads();                   // Xs reads done; sqX published

  // dist tile -> region0 (overwrites Xs). Row n's own col: sq==dot bitwise ->
  // (si+si) - 2*acc == 0 exactly.
  {
    float4 sj0 = sqX4[cg];
    float4 sj1 = sqX4[128 + cg];
    int jb = (n0 - s) + (h << 3);    // local col index of row 8h
#pragma unroll
    for (int r = 0; r < 8; ++r) {
      float si = sqX[jb + r];
      nf4 o0 = {si + sj0.x - 2.f * acc[r][0], si + sj0.y - 2.f * acc[r][1],
                si + sj0.z - 2.f * acc[r][2], si + sj0.w - 2.f * acc[r][3]};
      nf4 o1 = {si + sj1.x - 2.f * acc[r][4], si + sj1.y - 2.f * acc[r][5],
                si + sj1.z - 2.f * acc[r][6], si + sj1.w - 2.f * acc[r][7]};
      int row = (h << 3) + r;
      *(nf4*)&R0[(row << 10) + (cg << 2)] = o0;
      *(nf4*)&R0[(row << 10) + 512 + (cg << 2)] = o1;
    }
  }
  __syncthreads();

  // select: wave w owns local rows 4w..4w+3. Key = (orderable-dist<<32)|jj,
  // jj = 256q + 4*lane + e -> unique keys, smaller-index tie-break (lax.top_k).
  int lane = t & 63, w = t >> 6;
  float msum[4], xr[4];
  int cnt[4];
#pragma unroll 1
  for (int rr = 0; rr < 4; ++rr) {
    int rl = (w << 2) + rr;
    int n = n0 + rl;
    float xself = x[(((size_t)(n >> 10)) << 16) + ((size_t)lane << 10) + (n & 1023)];
    xr[rr] = xself;
    if (n == 8191) { msum[rr] = xself; cnt[rr] = 1; continue; }  // singleton batch
    cnt[rr] = 9;
    bool mlast = (n >= 7168);        // batch-7 rows exclude jj=1023 (node 8191)
    unsigned long long cand[16];
#pragma unroll
    for (int q = 0; q < 4; ++q) {
      nf4 v = *(const nf4*)&R0[(rl << 10) + (q << 8) + (lane << 2)];
      float vv[4] = {v.x, v.y, v.z, v.w};
#pragma unroll
      for (int e = 0; e < 4; ++e) {
        unsigned u = __float_as_uint(vv[e]);
        u = (u & 0x80000000u) ? ~u : (u | 0x80000000u);
        unsigned jj = (unsigned)((q << 8) + (lane << 2) + e);
        cand[(q << 2) + e] = ((unsigned long long)u << 32) | jj;
      }
    }
    if (mlast && lane == 63) cand[15] = ~0ull;   // jj=1023 -> q=3,lane=63,e=3
    // per-lane top-2 cache
    unsigned long long m1 = cand[0], m2 = cand[1];
    if (m2 < m1) { unsigned long long tt = m1; m1 = m2; m2 = tt; }
#pragma unroll
    for (int q = 2; q < 16; ++q) {
      unsigned long long c = cand[q];
      unsigned long long lo = (c < m1) ? c : m1;
      unsigned long long hi = (c < m1) ? m1 : c;
      m2 = (hi < m2) ? hi : m2;
      m1 = lo;
    }
    unsigned long long lm = m1;
    unsigned rmask = 0;
    bool stale = false;
    unsigned jloc[9];
#pragma unroll
    for (int kk = 0; kk < 9; ++kk) {
      unsigned long long g = lm;
#pragma unroll
      for (int off = 32; off; off >>= 1) {
        unsigned ghi = __shfl_xor((unsigned)(g >> 32), off, 64);
        unsigned glo = __shfl_xor((unsigned)g, off, 64);
        unsigned long long o = ((unsigned long long)ghi << 32) | glo;
        g = (o < g) ? o : g;
      }
      jloc[kk] = (unsigned)g & 1023u;
      if (lm == g) {                 // exactly one winner lane (unique keys)
        unsigned slot = (((unsigned)g >> 6) & 12u) | ((unsigned)g & 3u);
        rmask |= 1u << slot;
        if (!stale) { lm = m2; stale = true; }
        else {                       // rare: rescan excluding removed slots
          unsigned long long best = ~0ull;
#pragma unroll
          for (int q = 0; q < 16; ++q) {
            bool alive = ((rmask >> q) & 1u) == 0u;
            unsigned long long c = cand[q];
            best = (alive && c < best) ? c : best;
          }
          lm = best;
        }
      }
    }
    // 9 independent gathers (wave-uniform jj; addr = batch + lane*1024 + jj)
    const float* gx = xb + ((size_t)lane << 10);
    float g0 = gx[jloc[0]], g1 = gx[jloc[1]], g2 = gx[jloc[2]];
    float g3 = gx[jloc[3]], g4 = gx[jloc[4]], g5 = gx[jloc[5]];
    float g6 = gx[jloc[6]], g7 = gx[jloc[7]], g8 = gx[jloc[8]];
    msum[rr] = (((g0 + g1) + (g2 + g3)) + ((g4 + g5) + (g6 + g7))) + g8;
  }
  __syncthreads();                   // all dist reads done before Ws overlay

  // stage Ws over region0: WsL [64][65] @0, WsR @4160 (stride 65 -> 2/bank)
#pragma unroll 4
  for (int i = 0; i < 16; ++i) {
    int lin = t + (i << 8);
    int o = lin >> 6, c = lin & 63;
    R0[o * 65 + c] = Wl[lin];
    R0[4160 + o * 65 + c] = Wr[lin];
  }
  __syncthreads();

  // transform: lane = output channel o; mean-then-linear (= reference order)
  float bias = bl[lane];
  float ms[4];
#pragma unroll
  for (int rr = 0; rr < 4; ++rr)
    ms[rr] = (cnt[rr] == 9) ? msum[rr] * (1.f / 9.f) : msum[rr];
  float accL[4] = {0.f, 0.f, 0.f, 0.f};
  float accR[4] = {0.f, 0.f, 0.f, 0.f};
#pragma unroll
  for (int c = 0; c < 64; ++c) {
    float wlc = R0[lane * 65 + c];
    float wrc = R0[4160 + lane * 65 + c];
#pragma unroll
    for (int rr = 0; rr < 4; ++rr) {
      float mc = __int_as_float(__builtin_amdgcn_readlane(__float_as_int(ms[rr]), c));
      float xc = __int_as_float(__builtin_amdgcn_readlane(__float_as_int(xr[rr]), c));
      accL[rr] = fmaf(mc, wlc, accL[rr]);
      accR[rr] = fmaf(xc, wrc, accR[rr]);
    }
  }
#pragma unroll
  for (int rr = 0; rr < 4; ++rr)
    __builtin_nontemporal_store(accL[rr] + accR[rr] + bias,
                                &out[((size_t)(n0 + (w << 2) + rr) << 6) + lane]);
}

// ---------------------------------------------------------------------------
extern "C" void kernel_launch(void* const* d_in, const int* in_sizes, int n_in,
                              void* d_out, int out_size, void* d_ws, size_t ws_size,
                              hipStream_t stream) {
  const float* x  = (const float*)d_in[0];   // (8,64,32,32)
  const float* Wl = (const float*)d_in[1];   // (64,64)
  const float* bl = (const float*)d_in[2];   // (64,)
  const float* Wr = (const float*)d_in[3];   // (64,64)
  float* out = (float*)d_out;                // (8192,64)
  (void)d_ws; (void)ws_size;                 // workspace unused (no D buffer)

  k_all<<<dim3(512), 256, 0, stream>>>(x, Wl, bl, Wr, out);
}